// Round 1
// baseline (1138.796 us; speedup 1.0000x reference)
//
#include <hip/hip_runtime.h>
#include <math.h>
#include <float.h>

// Problem constants: B=64, H=W=32, C=256, D=H*W=1024, K=1024
#define B_   64
#define C_   256
#define D_   1024
#define K_   1024
#define M_   (B_ * C_)        // 16384 flat rows
#define NX_  (B_ * D_ * C_)   // 16777216 elements of x / q_out
#define DISC_OFF NX_          // 16777216
#define LOSS_OFF (NX_ + M_)   // 16793600

// ---------------------------------------------------------------------------
// k0: column norms of E (sum over d of E[d,k]^2) + zero the loss accumulator.
// Grid: 4 blocks x 256 threads (one thread per codebook column).
// ---------------------------------------------------------------------------
__global__ __launch_bounds__(256) void prep_kernel(const float* __restrict__ E,
                                                   float* __restrict__ colnorm,
                                                   float* __restrict__ loss_slot) {
    const int k = blockIdx.x * 256 + threadIdx.x;   // 0..1023
    float s0 = 0.f, s1 = 0.f, s2 = 0.f, s3 = 0.f;
    for (int d = 0; d < D_; d += 4) {
        float v0 = E[(d + 0) * K_ + k];
        float v1 = E[(d + 1) * K_ + k];
        float v2 = E[(d + 2) * K_ + k];
        float v3 = E[(d + 3) * K_ + k];
        s0 = fmaf(v0, v0, s0);
        s1 = fmaf(v1, v1, s1);
        s2 = fmaf(v2, v2, s2);
        s3 = fmaf(v3, v3, s3);
    }
    colnorm[k] = (s0 + s1) + (s2 + s3);
    if (k == 0) *loss_slot = 0.0f;
}

// ---------------------------------------------------------------------------
// k1: fused distance GEMM + argmin.
// flat[r, d] = x[(b*1024 + d)*256 + c]  with r = b*256 + c.
// Block = 64 consecutive rows (b fixed, c0..c0+63). Loops over all 16 N-tiles
// of 64 codebook columns, keeping a per-row running (min, argmin) so ties
// break to the smallest k (numpy argmin semantics).
// dist = (||f||^2 + ||e_k||^2) - 2*dot  (same formula/ordering as reference).
// ---------------------------------------------------------------------------
__global__ __launch_bounds__(256) void argmin_kernel(const float* __restrict__ x,
                                                     const float* __restrict__ E,
                                                     const float* __restrict__ colnorm,
                                                     float* __restrict__ disc_out) {
    __shared__ float As[32][64];     // [kk][row]   8 KB
    __shared__ float Bs[32][64];     // [kk][col]   8 KB
    __shared__ float sTile[64][65];  // scores      16.6 KB (pad breaks conflicts)
    __shared__ float rpart[4][64];
    __shared__ float rown[64];

    const int tid = threadIdx.x;
    const int rt  = blockIdx.x;          // row-tile 0..255
    const int b   = rt >> 2;             // batch index (4 tiles of 64 per b)
    const int c0  = (rt & 3) * 64;       // channel base
    const int tx  = tid & 15;            // 16 col-groups of 4
    const int ty  = tid >> 4;            // 16 row-groups of 4

    // --- row norms: thread (q,i) sums quarter q of row i ---
    {
        const int i = tid & 63;
        const int q = tid >> 6;          // 0..3
        const float* xp = x + (size_t)(b * 1024 + q * 256) * 256 + c0 + i;
        float s = 0.f;
        #pragma unroll 8
        for (int d = 0; d < 256; ++d) {
            float v = xp[(size_t)d * 256];
            s = fmaf(v, v, s);
        }
        rpart[q][i] = s;
    }
    __syncthreads();
    if (tid < 64)
        rown[tid] = (rpart[0][tid] + rpart[1][tid]) + (rpart[2][tid] + rpart[3][tid]);
    // rown is read only after the kt-loop's barriers below — ordering is safe.

    float bestVal = FLT_MAX;
    int   bestIdx = 0;

    for (int nt = 0; nt < 16; ++nt) {
        const int n0 = nt * 64;

        float acc[4][4];
        #pragma unroll
        for (int ii = 0; ii < 4; ++ii)
            #pragma unroll
            for (int jj = 0; jj < 4; ++jj)
                acc[ii][jj] = 0.f;

        for (int kt = 0; kt < 32; ++kt) {
            const int kb = kt * 32;
            __syncthreads();  // previous compute / scan done before overwrite
            #pragma unroll
            for (int p = 0; p < 8; ++p) {
                const int e  = tid + p * 256;
                const int kk = e >> 6;
                const int i  = e & 63;
                As[kk][i] = x[(size_t)(b * 1024 + kb + kk) * 256 + c0 + i];
                Bs[kk][i] = E[(kb + kk) * K_ + n0 + i];
            }
            __syncthreads();
            #pragma unroll
            for (int kk = 0; kk < 32; ++kk) {
                const float4 av = *reinterpret_cast<const float4*>(&As[kk][ty * 4]);
                const float4 bv = *reinterpret_cast<const float4*>(&Bs[kk][tx * 4]);
                const float a4[4] = {av.x, av.y, av.z, av.w};
                const float b4[4] = {bv.x, bv.y, bv.z, bv.w};
                #pragma unroll
                for (int ii = 0; ii < 4; ++ii)
                    #pragma unroll
                    for (int jj = 0; jj < 4; ++jj)
                        acc[ii][jj] = fmaf(a4[ii], b4[jj], acc[ii][jj]);
            }
        }
        __syncthreads();

        // scores -> sTile
        #pragma unroll
        for (int ii = 0; ii < 4; ++ii) {
            const float rn = rown[ty * 4 + ii];
            #pragma unroll
            for (int jj = 0; jj < 4; ++jj) {
                const float cn = colnorm[n0 + tx * 4 + jj];
                sTile[ty * 4 + ii][tx * 4 + jj] = (rn + cn) - 2.0f * acc[ii][jj];
            }
        }
        __syncthreads();

        // per-row argmin update, increasing j => first-index tie-break
        if (tid < 64) {
            #pragma unroll 8
            for (int j = 0; j < 64; ++j) {
                const float v = sTile[tid][j];
                if (v < bestVal) { bestVal = v; bestIdx = n0 + j; }
            }
        }
        __syncthreads();
    }

    if (tid < 64) {
        disc_out[rt * 64 + tid] = (float)bestIdx;  // r = b*256 + c0 + tid
    }
}

// ---------------------------------------------------------------------------
// k2: q_out = x + (E[:,idx] - x)  (exactly the reference's rounding),
// plus loss = 1.25 * mean((x - q)^2), block-reduced, one atomicAdd/block.
// Each thread handles 4 consecutive elements (same b,d; c..c+3).
// Grid: 16384 blocks x 256 threads.
// ---------------------------------------------------------------------------
__global__ __launch_bounds__(256) void finalize_kernel(const float* __restrict__ x,
                                                       const float* __restrict__ E,
                                                       const float* __restrict__ discf,
                                                       float* __restrict__ out,
                                                       float* __restrict__ loss) {
    const int gid = blockIdx.x * 256 + threadIdx.x;
    const int g   = gid << 2;              // element base, multiple of 4
    const int c   = g & 255;
    const int d   = (g >> 8) & 1023;
    const int b   = g >> 18;

    const float4 xv = *reinterpret_cast<const float4*>(x + g);
    const int r0 = b * 256 + c;
    const int i0 = (int)discf[r0 + 0];
    const int i1 = (int)discf[r0 + 1];
    const int i2 = (int)discf[r0 + 2];
    const int i3 = (int)discf[r0 + 3];

    const float* Ed = E + d * K_;
    const float e0 = Ed[i0];
    const float e1 = Ed[i1];
    const float e2 = Ed[i2];
    const float e3 = Ed[i3];

    float4 qv;
    qv.x = xv.x + (e0 - xv.x);
    qv.y = xv.y + (e1 - xv.y);
    qv.z = xv.z + (e2 - xv.z);
    qv.w = xv.w + (e3 - xv.w);
    *reinterpret_cast<float4*>(out + g) = qv;

    const float d0 = xv.x - e0, d1 = xv.y - e1, d2 = xv.z - e2, d3 = xv.w - e3;
    float local = fmaf(d0, d0, fmaf(d1, d1, fmaf(d2, d2, d3 * d3)));

    #pragma unroll
    for (int off = 32; off > 0; off >>= 1)
        local += __shfl_down(local, off);

    __shared__ float wsum[4];
    if ((threadIdx.x & 63) == 0) wsum[threadIdx.x >> 6] = local;
    __syncthreads();
    if (threadIdx.x == 0) {
        const float s = (wsum[0] + wsum[1]) + (wsum[2] + wsum[3]);
        atomicAdd(loss, s * (1.25f / 16777216.0f));
    }
}

// ---------------------------------------------------------------------------
extern "C" void kernel_launch(void* const* d_in, const int* in_sizes, int n_in,
                              void* d_out, int out_size, void* d_ws, size_t ws_size,
                              hipStream_t stream) {
    const float* x = (const float*)d_in[0];   // (64,32,32,256) f32
    const float* E = (const float*)d_in[1];   // (1024,1024)    f32
    float* out     = (float*)d_out;
    float* colnorm = (float*)d_ws;            // 1024 floats of scratch
    float* disc    = out + DISC_OFF;
    float* loss    = out + LOSS_OFF;

    prep_kernel<<<4, 256, 0, stream>>>(E, colnorm, loss);
    argmin_kernel<<<256, 256, 0, stream>>>(x, E, colnorm, disc);
    finalize_kernel<<<NX_ / 1024, 256, 0, stream>>>(x, E, disc, out, loss);
}

// Round 2
// 462.597 us; speedup vs baseline: 2.4617x; 2.4617x over previous
//
#include <hip/hip_runtime.h>
#include <float.h>

// Problem constants: B=64, H=W=32, C=256, D=H*W=1024, K=1024
#define B_   64
#define C_   256
#define D_   1024
#define K_   1024
#define M_   (B_ * C_)        // 16384 flat rows
#define NX_  (B_ * D_ * C_)   // 16777216 elements of x / q_out
#define DISC_OFF NX_
#define LOSS_OFF (NX_ + M_)

// Scratch lives in the q-region of d_out (finalize overwrites it all at the end).
// Offsets in floats:
#define EH_OFF   0            // 1M fp16 = 524288 floats
#define EL_OFF   524288
#define CN_OFF   1048576      // 1024 floats
#define PV_OFF   1049600      // 16384*8 floats (per-ct argmin partial values)
#define PI_OFF   1180672      // 16384*8 ints   (per-ct argmin partial indices)
#define PCN_OFF  1311744      // 16*1024 floats (colnorm partials)

typedef _Float16 h8 __attribute__((ext_vector_type(8)));
typedef _Float16 h4 __attribute__((ext_vector_type(4)));
typedef float    f4 __attribute__((ext_vector_type(4)));

// Split scales (powers of two; exact). dot_scaled = 512*2048*dot = 2^20 * dot.
#define XSCALE 512.0f
#define ESCALE 2048.0f
#define DOT_UNSCALE_2 (2.0f / 1048576.0f)   // converts acc -> 2*dot

// ---------------------------------------------------------------------------
// colnorm stage 1: partial sums of E[:,k]^2 over 64-d chunks.
// Grid 64 x 256: block (kc = bi&3 gives 256 cols, dc = bi>>2 gives 64 d's).
// ---------------------------------------------------------------------------
__global__ __launch_bounds__(256) void colnorm1_kernel(const float* __restrict__ E,
                                                       float* __restrict__ pcn) {
    const int k  = (blockIdx.x & 3) * 256 + threadIdx.x;
    const int dc = blockIdx.x >> 2;          // 0..15
    const float* Ep = E + (size_t)(dc * 64) * K_ + k;
    float s0 = 0.f, s1 = 0.f;
    #pragma unroll
    for (int d = 0; d < 64; d += 2) {
        float v0 = Ep[(size_t)d * K_];
        float v1 = Ep[(size_t)(d + 1) * K_];
        s0 = fmaf(v0, v0, s0);
        s1 = fmaf(v1, v1, s1);
    }
    pcn[dc * K_ + k] = s0 + s1;
}

// colnorm stage 2: sum the 16 partials; also zero the loss slot.
__global__ __launch_bounds__(256) void colnorm2_kernel(const float* __restrict__ pcn,
                                                       float* __restrict__ cn,
                                                       float* __restrict__ loss_slot) {
    const int k = blockIdx.x * 256 + threadIdx.x;
    float s = 0.f;
    #pragma unroll
    for (int i = 0; i < 16; ++i) s += pcn[i * K_ + k];
    cn[k] = s;
    if (k == 0) *loss_slot = 0.0f;
}

// ---------------------------------------------------------------------------
// E transpose + fp16 hi/lo split: Eh/El[n][k] = split(E[k][n] * ESCALE).
// Grid 256 blocks (16x16 tiles of 64x64) x 256 threads.
// ---------------------------------------------------------------------------
__global__ __launch_bounds__(256) void esplit_kernel(const float* __restrict__ E,
                                                     _Float16* __restrict__ Eh,
                                                     _Float16* __restrict__ El) {
    __shared__ float tile[64][65];
    const int t  = threadIdx.x;
    const int n0 = (blockIdx.x & 15) * 64;
    const int d0 = (blockIdx.x >> 4) * 64;
    const int cl = t & 63, rg = t >> 6;   // 4 row-groups of 16
    #pragma unroll 4
    for (int r = 0; r < 16; ++r) {
        const int dl = rg * 16 + r;
        tile[dl][cl] = E[(size_t)(d0 + dl) * K_ + n0 + cl];
    }
    __syncthreads();
    #pragma unroll 4
    for (int r = 0; r < 16; ++r) {
        const int nl = rg * 16 + r;
        const float vs = tile[cl][nl] * ESCALE;
        const _Float16 h = (_Float16)vs;
        const _Float16 l = (_Float16)(vs - (float)h);
        Eh[(size_t)(n0 + nl) * K_ + d0 + cl] = h;
        El[(size_t)(n0 + nl) * K_ + d0 + cl] = l;
    }
}

// ---------------------------------------------------------------------------
// Fused split-fp16 MFMA distance GEMM + per-block argmin.
// Grid 1024 = 128 row-tiles x 8 col-tiles. Block: 256 thr = 4 waves,
// 128x128 output tile, BK=32 (one 16x16x32 MFMA k-chunk per step).
// Per (m,n) tile per k-step: 3 MFMAs (hh, hl, lh) into one fp32 acc.
// dist_partial(n) = cn[n] - 2*dot  (row norm dropped: constant per row).
// ---------------------------------------------------------------------------
__global__ __launch_bounds__(256, 2) void gemm_argmin_kernel(
        const float* __restrict__ x,
        const _Float16* __restrict__ Eh,
        const _Float16* __restrict__ El,
        const float* __restrict__ cn,
        float* __restrict__ pV,
        int* __restrict__ pI) {
    __shared__ __align__(16) _Float16 Ash[2][128][40];  // [plane][m][k] pad 32->40
    __shared__ __align__(16) _Float16 Bsh[2][128][40];  // [plane][n][k]
    __shared__ float cV[128][2];
    __shared__ int   cI[128][2];

    const int t    = threadIdx.x;
    const int rt   = blockIdx.x >> 3;       // 0..127
    const int ct   = blockIdx.x & 7;        // 0..7
    const int b    = rt >> 1;               // batch
    const int c0   = (rt & 1) * 128;        // channel base
    const int n0g  = ct * 128;              // global col base

    const int wave = t >> 6;
    const int lane = t & 63;
    const int lo16 = lane & 15;
    const int hi4  = lane >> 4;
    const int mq   = (wave & 1) * 64;       // wave m-quadrant
    const int nq   = (wave >> 1) * 64;      // wave n-quadrant

    // A-staging ids: thread covers 4 k (km*4..+3) x 4 m (mg*4..+3)
    const int km = t & 7;
    const int mg = t >> 3;                  // 0..31

    f4 acc[4][4];
    const f4 zero = {0.f, 0.f, 0.f, 0.f};
    #pragma unroll
    for (int i = 0; i < 4; ++i)
        #pragma unroll
        for (int j = 0; j < 4; ++j) acc[i][j] = zero;

    for (int ks = 0; ks < 32; ++ks) {
        __syncthreads();
        // ---- A stage: load f32, split to fp16 hi/lo, 4x4 register transpose ----
        {
            const float* xp = x + ((size_t)(b * 1024 + ks * 32 + km * 4)) * 256 + c0 + mg * 4;
            float4 f[4];
            #pragma unroll
            for (int kk = 0; kk < 4; ++kk)
                f[kk] = *(const float4*)(xp + (size_t)kk * 256);
            #pragma unroll
            for (int mi = 0; mi < 4; ++mi) {
                h4 hh, ll;
                #pragma unroll
                for (int kk = 0; kk < 4; ++kk) {
                    const float vs = ((const float*)&f[kk])[mi] * XSCALE;
                    const _Float16 h = (_Float16)vs;
                    hh[kk] = h;
                    ll[kk] = (_Float16)(vs - (float)h);
                }
                const int m = mg * 4 + mi;
                *(h4*)&Ash[0][m][km * 4] = hh;
                *(h4*)&Ash[1][m][km * 4] = ll;
            }
        }
        // ---- B stage: 16B chunks from pre-split [n][k] planes ----
        {
            #pragma unroll
            for (int p = 0; p < 2; ++p) {
                const int cid = t + p * 256;        // 0..511
                const int n   = cid >> 2;           // 0..127
                const int kc  = cid & 3;            // 0..3
                const size_t g = (size_t)(n0g + n) * K_ + ks * 32 + kc * 8;
                *(h8*)&Bsh[0][n][kc * 8] = *(const h8*)(Eh + g);
                *(h8*)&Bsh[1][n][kc * 8] = *(const h8*)(El + g);
            }
        }
        __syncthreads();
        // ---- compute: 16 fragment reads + 48 MFMAs ----
        h8 Af[2][4], Bf[2][4];
        #pragma unroll
        for (int tm = 0; tm < 4; ++tm) {
            Af[0][tm] = *(const h8*)&Ash[0][mq + tm * 16 + lo16][hi4 * 8];
            Af[1][tm] = *(const h8*)&Ash[1][mq + tm * 16 + lo16][hi4 * 8];
            Bf[0][tm] = *(const h8*)&Bsh[0][nq + tm * 16 + lo16][hi4 * 8];
            Bf[1][tm] = *(const h8*)&Bsh[1][nq + tm * 16 + lo16][hi4 * 8];
        }
        #pragma unroll
        for (int tm = 0; tm < 4; ++tm)
            #pragma unroll
            for (int tn = 0; tn < 4; ++tn) {
                acc[tm][tn] = __builtin_amdgcn_mfma_f32_16x16x32_f16(Af[0][tm], Bf[0][tn], acc[tm][tn], 0, 0, 0);
                acc[tm][tn] = __builtin_amdgcn_mfma_f32_16x16x32_f16(Af[0][tm], Bf[1][tn], acc[tm][tn], 0, 0, 0);
                acc[tm][tn] = __builtin_amdgcn_mfma_f32_16x16x32_f16(Af[1][tm], Bf[0][tn], acc[tm][tn], 0, 0, 0);
            }
    }

    // ---- epilogue: per-row argmin over this block's 128 cols ----
    float cnv[4];
    #pragma unroll
    for (int tn = 0; tn < 4; ++tn) cnv[tn] = cn[n0g + nq + tn * 16 + lo16];

    #pragma unroll
    for (int tm = 0; tm < 4; ++tm) {
        #pragma unroll
        for (int r = 0; r < 4; ++r) {
            float bv = FLT_MAX;
            int   bi = 0;
            #pragma unroll
            for (int tn = 0; tn < 4; ++tn) {   // ascending col, strict < => first-index tie-break
                const float v = cnv[tn] - acc[tm][tn][r] * DOT_UNSCALE_2;
                if (v < bv) { bv = v; bi = nq + tn * 16 + lo16; }
            }
            #pragma unroll
            for (int msk = 1; msk < 16; msk <<= 1) {
                const float ov = __shfl_xor(bv, msk, 64);
                const int   oi = __shfl_xor(bi, msk, 64);
                if (ov < bv || (ov == bv && oi < bi)) { bv = ov; bi = oi; }
            }
            if (lo16 == 0) {
                const int row = mq + tm * 16 + hi4 * 4 + r;
                cV[row][wave >> 1] = bv;
                cI[row][wave >> 1] = bi;
            }
        }
    }
    __syncthreads();
    if (t < 128) {
        const float v0 = cV[t][0], v1 = cV[t][1];
        const int   i0 = cI[t][0], i1 = cI[t][1];
        float bv; int bi;
        if (v1 < v0) { bv = v1; bi = i1; } else { bv = v0; bi = i0; }  // tie -> lower cols
        const int row = rt * 128 + t;
        pV[row * 8 + ct] = bv;
        pI[row * 8 + ct] = n0g + bi;
    }
}

// ---------------------------------------------------------------------------
// Final argmin across the 8 col-tiles (ascending ct, strict < => numpy tie-break).
// ---------------------------------------------------------------------------
__global__ __launch_bounds__(256) void reduce_kernel(const float* __restrict__ pV,
                                                     const int* __restrict__ pI,
                                                     float* __restrict__ disc) {
    const int rid = blockIdx.x * 256 + threadIdx.x;
    float bv = FLT_MAX;
    int   bi = 0;
    #pragma unroll
    for (int c = 0; c < 8; ++c) {
        const float v = pV[rid * 8 + c];
        const int   i = pI[rid * 8 + c];
        if (v < bv || (v == bv && i < bi)) { bv = v; bi = i; }
    }
    disc[rid] = (float)bi;
}

// ---------------------------------------------------------------------------
// q_out = x + (E[:,idx] - x); loss = 1.25 * mean((x - q)^2).
// ---------------------------------------------------------------------------
__global__ __launch_bounds__(256) void finalize_kernel(const float* __restrict__ x,
                                                       const float* __restrict__ E,
                                                       const float* __restrict__ discf,
                                                       float* __restrict__ out,
                                                       float* __restrict__ loss) {
    const int gid = blockIdx.x * 256 + threadIdx.x;
    const int g   = gid << 2;
    const int c   = g & 255;
    const int d   = (g >> 8) & 1023;
    const int b   = g >> 18;

    const float4 xv = *reinterpret_cast<const float4*>(x + g);
    const int r0 = b * 256 + c;
    const int i0 = (int)discf[r0 + 0];
    const int i1 = (int)discf[r0 + 1];
    const int i2 = (int)discf[r0 + 2];
    const int i3 = (int)discf[r0 + 3];

    const float* Ed = E + (size_t)d * K_;
    const float e0 = Ed[i0];
    const float e1 = Ed[i1];
    const float e2 = Ed[i2];
    const float e3 = Ed[i3];

    float4 qv;
    qv.x = xv.x + (e0 - xv.x);
    qv.y = xv.y + (e1 - xv.y);
    qv.z = xv.z + (e2 - xv.z);
    qv.w = xv.w + (e3 - xv.w);
    *reinterpret_cast<float4*>(out + g) = qv;

    const float d0 = xv.x - e0, d1 = xv.y - e1, d2 = xv.z - e2, d3 = xv.w - e3;
    float local = fmaf(d0, d0, fmaf(d1, d1, fmaf(d2, d2, d3 * d3)));

    #pragma unroll
    for (int off = 32; off > 0; off >>= 1)
        local += __shfl_down(local, off);

    __shared__ float wsum[4];
    if ((threadIdx.x & 63) == 0) wsum[threadIdx.x >> 6] = local;
    __syncthreads();
    if (threadIdx.x == 0) {
        const float s = (wsum[0] + wsum[1]) + (wsum[2] + wsum[3]);
        atomicAdd(loss, s * (1.25f / 16777216.0f));
    }
}

// ---------------------------------------------------------------------------
extern "C" void kernel_launch(void* const* d_in, const int* in_sizes, int n_in,
                              void* d_out, int out_size, void* d_ws, size_t ws_size,
                              hipStream_t stream) {
    (void)d_ws; (void)ws_size; (void)in_sizes; (void)n_in; (void)out_size;
    const float* x = (const float*)d_in[0];   // (64,32,32,256) f32
    const float* E = (const float*)d_in[1];   // (1024,1024)    f32
    float* out = (float*)d_out;

    _Float16* Eh = (_Float16*)(out + EH_OFF);
    _Float16* El = (_Float16*)(out + EL_OFF);
    float* cnrm  = out + CN_OFF;
    float* pV    = out + PV_OFF;
    int*   pI    = (int*)(out + PI_OFF);
    float* pcn   = out + PCN_OFF;
    float* disc  = out + DISC_OFF;
    float* loss  = out + LOSS_OFF;

    colnorm1_kernel<<<64, 256, 0, stream>>>(E, pcn);
    colnorm2_kernel<<<4, 256, 0, stream>>>(pcn, cnrm, loss);
    esplit_kernel<<<256, 256, 0, stream>>>(E, Eh, El);
    gemm_argmin_kernel<<<1024, 256, 0, stream>>>(x, Eh, El, cnrm, pV, pI);
    reduce_kernel<<<64, 256, 0, stream>>>(pV, pI, disc);
    finalize_kernel<<<NX_ / 1024, 256, 0, stream>>>(x, E, disc, out, loss);
}

// Round 3
// 274.371 us; speedup vs baseline: 4.1506x; 1.6860x over previous
//
#include <hip/hip_runtime.h>
#include <float.h>
#include <stdint.h>

// Problem constants: B=64, H=W=32, C=256, D=H*W=1024, K=1024
#define B_   64
#define C_   256
#define D_   1024
#define K_   1024
#define M_   16384
#define NX_  16777216          // B*D*C = M*D
#define DISC_OFF NX_
#define LOSS_OFF (NX_ + M_)

typedef _Float16 h8 __attribute__((ext_vector_type(8)));
typedef float    f4 __attribute__((ext_vector_type(4)));

// Power-of-2 split scales (exact). acc = 2^20 * dot.
#define XSCALE 512.0f
#define ESCALE 2048.0f
#define DOT_UNSCALE_2 (2.0f / 1048576.0f)

// d_ws layout (float offsets). Total need ~5.6 MB.
#define WS_EH  0          // 1M fp16 = 524288 floats
#define WS_EL  524288
#define WS_CN  1048576    // 1024
#define WS_PCN 1049600    // 128*1024
#define WS_PV  1180672    // 16384*8
#define WS_PI  1311744    // 16384*8

// xh/xl fragment-tiled planes live in the q-region of d_out:
// plane = NX_ fp16 elements (33.5 MB); two planes fill the region exactly.

__device__ __forceinline__ void async16(const _Float16* g, _Float16* l) {
    __builtin_amdgcn_global_load_lds(
        (const __attribute__((address_space(1))) unsigned int*)g,
        (__attribute__((address_space(3))) unsigned int*)l, 16, 0, 0);
}

// ---------------------------------------------------------------------------
// E -> fragment-tiled fp16 hi/lo planes [nt][kt][lane][8] + colnorm partials.
// Thread (n, o): 8 elements E[o*8 .. o*8+7][n]. Grid 512 x 256.
// ---------------------------------------------------------------------------
__global__ __launch_bounds__(256) void esplit_kernel(const float* __restrict__ E,
                                                     _Float16* __restrict__ Eh,
                                                     _Float16* __restrict__ El,
                                                     float* __restrict__ pcn) {
    const int tid = blockIdx.x * 256 + threadIdx.x;   // [0, 131072)
    const int n   = tid & 1023;
    const int o   = tid >> 10;                        // k-octet [0,128)
    const int d0  = o * 8;
    h8 hh, ll;
    float s = 0.f;
    #pragma unroll
    for (int i = 0; i < 8; ++i) {
        const float v = E[(size_t)(d0 + i) * K_ + n];
        s = fmaf(v, v, s);
        const float vs = v * ESCALE;
        const _Float16 h = (_Float16)vs;
        hh[i] = h;
        ll[i] = (_Float16)(vs - (float)h);
    }
    pcn[o * K_ + n] = s;
    const int nt   = n >> 4;
    const int kt   = o >> 2;
    const int lane = (n & 15) + (o & 3) * 16;
    const size_t off = ((size_t)(nt * 32 + kt) * 64 + lane) * 8;
    *(h8*)(Eh + off) = hh;
    *(h8*)(El + off) = ll;
}

// colnorm: sum the 128 partials per column; zero the loss slot.
__global__ __launch_bounds__(256) void colnorm2_kernel(const float* __restrict__ pcn,
                                                       float* __restrict__ cn,
                                                       float* __restrict__ loss_slot) {
    const int k = blockIdx.x * 256 + threadIdx.x;
    float s = 0.f;
    for (int i = 0; i < 128; ++i) s += pcn[i * K_ + k];
    cn[k] = s;
    if (k == 0) *loss_slot = 0.0f;
}

// ---------------------------------------------------------------------------
// x -> fragment-tiled fp16 hi/lo planes [mt][kt][lane][8], m=(b,c), k=d.
// Thread (m, o): 8 strided loads (coalesced across wave). Grid 8192 x 256.
// ---------------------------------------------------------------------------
__global__ __launch_bounds__(256) void xsplit_kernel(const float* __restrict__ x,
                                                     _Float16* __restrict__ Xh,
                                                     _Float16* __restrict__ Xl) {
    const int tid = blockIdx.x * 256 + threadIdx.x;   // [0, 2097152)
    const int m   = tid & 16383;
    const int o   = tid >> 14;                        // [0,128)
    const int b   = m >> 8, c = m & 255;
    const int d0  = o * 8;
    const float* xp = x + ((size_t)(b * 1024 + d0) * 256) + c;
    h8 hh, ll;
    #pragma unroll
    for (int i = 0; i < 8; ++i) {
        const float v  = xp[(size_t)i * 256];
        const float vs = v * XSCALE;
        const _Float16 h = (_Float16)vs;
        hh[i] = h;
        ll[i] = (_Float16)(vs - (float)h);
    }
    const int mt   = m >> 4;
    const int kt   = o >> 2;
    const int lane = (m & 15) + (o & 3) * 16;
    const size_t off = ((size_t)(mt * 32 + kt) * 64 + lane) * 8;
    *(h8*)(Xh + off) = hh;
    *(h8*)(Xl + off) = ll;
}

// ---------------------------------------------------------------------------
// Split-fp16 MFMA distance GEMM + per-block argmin.
// Grid 1024 = 128 row-tiles x 8 col-tiles (ct = bid&7 -> XCD swizzle for
// B-side L2 locality). 128x128 tile, BK=32. All staging via global_load_lds
// from fragment-tiled planes; LDS layout == fragment layout (conflict-free).
// ---------------------------------------------------------------------------
__global__ __launch_bounds__(256, 3) void gemm_argmin_kernel(
        const _Float16* __restrict__ Xh, const _Float16* __restrict__ Xl,
        const _Float16* __restrict__ Eh, const _Float16* __restrict__ El,
        const float* __restrict__ cn,
        float* __restrict__ pV, int* __restrict__ pI) {
    __shared__ _Float16 Abuf[16 * 512];   // [plane(2)][mt(8)][512]  16 KB
    __shared__ _Float16 Bbuf[16 * 512];   // [plane(2)][nt(8)][512]  16 KB
    __shared__ float cV[128][2];
    __shared__ int   cI[128][2];

    const int t    = threadIdx.x;
    const int rt   = blockIdx.x >> 3;     // 0..127
    const int ct   = blockIdx.x & 7;      // 0..7
    const int wave = t >> 6, lane = t & 63;
    const int lo16 = lane & 15, hi4 = lane >> 4;
    const int mq   = (wave & 1) * 64;
    const int nq   = (wave >> 1) * 64;
    const int mt0  = rt * 8, nt0 = ct * 8;
    const int n0g  = ct * 128;

    // 32 async tile-loads per k-step, 8 per wave: id = wave*8+i
    // id 0..7: A hi, 8..15: A lo, 16..23: B hi, 24..31: B lo
    const _Float16* gsrc[8];
    _Float16*       ldst[8];
    #pragma unroll
    for (int i = 0; i < 8; ++i) {
        const int id  = wave * 8 + i;
        const int p   = (id >> 3) & 1;
        const int tix = id & 7;
        if (id < 16) {
            const _Float16* base = p ? Xl : Xh;
            gsrc[i] = base + ((size_t)(mt0 + tix) * 32) * 512 + lane * 8;
            ldst[i] = &Abuf[(p * 8 + tix) * 512];
        } else {
            const _Float16* base = p ? El : Eh;
            gsrc[i] = base + ((size_t)(nt0 + tix) * 32) * 512 + lane * 8;
            ldst[i] = &Bbuf[(p * 8 + tix) * 512];
        }
    }

    f4 acc[4][4];
    const f4 zero = {0.f, 0.f, 0.f, 0.f};
    #pragma unroll
    for (int i = 0; i < 4; ++i)
        #pragma unroll
        for (int j = 0; j < 4; ++j) acc[i][j] = zero;

    for (int ks = 0; ks < 32; ++ks) {
        __syncthreads();                       // LDS free to overwrite
        #pragma unroll
        for (int i = 0; i < 8; ++i)
            async16(gsrc[i] + ks * 512, ldst[i]);
        __syncthreads();                       // vmcnt(0) drain + barrier

        h8 Bf[2][4];
        #pragma unroll
        for (int tn = 0; tn < 4; ++tn) {
            const int tixn = (nq >> 4) + tn;
            Bf[0][tn] = *(const h8*)&Bbuf[tixn * 512 + lane * 8];
            Bf[1][tn] = *(const h8*)&Bbuf[(8 + tixn) * 512 + lane * 8];
        }
        #pragma unroll
        for (int tm = 0; tm < 4; ++tm) {
            const int tixm = (mq >> 4) + tm;
            const h8 Ah = *(const h8*)&Abuf[tixm * 512 + lane * 8];
            const h8 Al = *(const h8*)&Abuf[(8 + tixm) * 512 + lane * 8];
            #pragma unroll
            for (int tn = 0; tn < 4; ++tn) {
                acc[tm][tn] = __builtin_amdgcn_mfma_f32_16x16x32_f16(Ah, Bf[0][tn], acc[tm][tn], 0, 0, 0);
                acc[tm][tn] = __builtin_amdgcn_mfma_f32_16x16x32_f16(Ah, Bf[1][tn], acc[tm][tn], 0, 0, 0);
                acc[tm][tn] = __builtin_amdgcn_mfma_f32_16x16x32_f16(Al, Bf[0][tn], acc[tm][tn], 0, 0, 0);
            }
        }
    }

    // ---- epilogue: per-row argmin over this block's 128 cols ----
    float cnv[4];
    #pragma unroll
    for (int tn = 0; tn < 4; ++tn) cnv[tn] = cn[n0g + nq + tn * 16 + lo16];

    #pragma unroll
    for (int tm = 0; tm < 4; ++tm) {
        #pragma unroll
        for (int r = 0; r < 4; ++r) {
            float bv = FLT_MAX;
            int   bi = 0;
            #pragma unroll
            for (int tn = 0; tn < 4; ++tn) {   // ascending col => first-index tie-break
                const float v = cnv[tn] - acc[tm][tn][r] * DOT_UNSCALE_2;
                if (v < bv) { bv = v; bi = nq + tn * 16 + lo16; }
            }
            #pragma unroll
            for (int msk = 1; msk < 16; msk <<= 1) {
                const float ov = __shfl_xor(bv, msk, 64);
                const int   oi = __shfl_xor(bi, msk, 64);
                if (ov < bv || (ov == bv && oi < bi)) { bv = ov; bi = oi; }
            }
            if (lo16 == 0) {
                const int row = mq + tm * 16 + hi4 * 4 + r;
                cV[row][wave >> 1] = bv;
                cI[row][wave >> 1] = bi;
            }
        }
    }
    __syncthreads();
    if (t < 128) {
        const float v0 = cV[t][0], v1 = cV[t][1];
        const int   i0 = cI[t][0], i1 = cI[t][1];
        float bv; int bi;
        if (v1 < v0) { bv = v1; bi = i1; } else { bv = v0; bi = i0; }
        const int row = rt * 128 + t;
        pV[row * 8 + ct] = bv;
        pI[row * 8 + ct] = n0g + bi;
    }
}

// ---------------------------------------------------------------------------
// Final argmin across the 8 col-tiles (ascending, numpy tie-break).
// ---------------------------------------------------------------------------
__global__ __launch_bounds__(256) void reduce_kernel(const float* __restrict__ pV,
                                                     const int* __restrict__ pI,
                                                     float* __restrict__ disc) {
    const int rid = blockIdx.x * 256 + threadIdx.x;
    float bv = FLT_MAX;
    int   bi = 0;
    #pragma unroll
    for (int c = 0; c < 8; ++c) {
        const float v = pV[rid * 8 + c];
        const int   i = pI[rid * 8 + c];
        if (v < bv || (v == bv && i < bi)) { bv = v; bi = i; }
    }
    disc[rid] = (float)bi;
}

// ---------------------------------------------------------------------------
// finalize: one block per d. E row d staged in LDS (4 KB), gather via ds_read.
// q = x + (e - x); loss += 1.25*mean((x-e)^2). Fully coalesced x/q streams.
// ---------------------------------------------------------------------------
__global__ __launch_bounds__(256) void finalize_kernel(const float* __restrict__ x,
                                                       const float* __restrict__ E,
                                                       const float* __restrict__ discf,
                                                       float* __restrict__ out,
                                                       float* __restrict__ loss) {
    __shared__ float Erow[1024];
    const int t = threadIdx.x;
    const int d = blockIdx.x;
    *(float4*)&Erow[t * 4] = *(const float4*)(E + (size_t)d * K_ + t * 4);
    __syncthreads();

    const int bl = t >> 6;           // wave id -> b offset
    const int c4 = (t & 63) * 4;
    float lsum = 0.f;
    #pragma unroll 4
    for (int bg = 0; bg < 64; bg += 4) {
        const int b = bg + bl;
        const float4 id4 = *(const float4*)(discf + b * 256 + c4);
        const size_t xoff = ((size_t)(b * 1024 + d) << 8) + c4;
        const float4 xv = *(const float4*)(x + xoff);
        const float e0 = Erow[(int)id4.x];
        const float e1 = Erow[(int)id4.y];
        const float e2 = Erow[(int)id4.z];
        const float e3 = Erow[(int)id4.w];
        float4 qv;
        qv.x = xv.x + (e0 - xv.x);
        qv.y = xv.y + (e1 - xv.y);
        qv.z = xv.z + (e2 - xv.z);
        qv.w = xv.w + (e3 - xv.w);
        *(float4*)(out + xoff) = qv;
        const float d0 = xv.x - e0, d1 = xv.y - e1, d2 = xv.z - e2, d3 = xv.w - e3;
        lsum += fmaf(d0, d0, fmaf(d1, d1, fmaf(d2, d2, d3 * d3)));
    }

    #pragma unroll
    for (int off = 32; off > 0; off >>= 1)
        lsum += __shfl_down(lsum, off);
    __shared__ float wsum[4];
    if ((t & 63) == 0) wsum[t >> 6] = lsum;
    __syncthreads();
    if (t == 0) {
        const float s = (wsum[0] + wsum[1]) + (wsum[2] + wsum[3]);
        atomicAdd(loss, s * (1.25f / 16777216.0f));
    }
}

// ---------------------------------------------------------------------------
extern "C" void kernel_launch(void* const* d_in, const int* in_sizes, int n_in,
                              void* d_out, int out_size, void* d_ws, size_t ws_size,
                              hipStream_t stream) {
    (void)in_sizes; (void)n_in; (void)out_size; (void)ws_size;
    const float* x = (const float*)d_in[0];   // (64,32,32,256) f32
    const float* E = (const float*)d_in[1];   // (1024,1024)    f32
    float* out = (float*)d_out;
    float* ws  = (float*)d_ws;

    _Float16* Eh = (_Float16*)(ws + WS_EH);
    _Float16* El = (_Float16*)(ws + WS_EL);
    float* cn    = ws + WS_CN;
    float* pcn   = ws + WS_PCN;
    float* pV    = ws + WS_PV;
    int*   pI    = (int*)(ws + WS_PI);

    _Float16* Xh = (_Float16*)out;            // q-region scratch (overwritten by finalize)
    _Float16* Xl = (_Float16*)out + NX_;
    float* disc  = out + DISC_OFF;
    float* loss  = out + LOSS_OFF;

    esplit_kernel  <<<512,  256, 0, stream>>>(E, Eh, El, pcn);
    colnorm2_kernel<<<4,    256, 0, stream>>>(pcn, cn, loss);
    xsplit_kernel  <<<8192, 256, 0, stream>>>(x, Xh, Xl);
    gemm_argmin_kernel<<<1024, 256, 0, stream>>>(Xh, Xl, Eh, El, cn, pV, pI);
    reduce_kernel  <<<64,   256, 0, stream>>>(pV, pI, disc);
    finalize_kernel<<<1024, 256, 0, stream>>>(x, E, disc, out, loss);
}

// Round 4
// 249.216 us; speedup vs baseline: 4.5695x; 1.1009x over previous
//
#include <hip/hip_runtime.h>
#include <float.h>
#include <stdint.h>

// Problem constants: B=64, H=W=32, C=256, D=H*W=1024, K=1024
#define B_   64
#define C_   256
#define D_   1024
#define K_   1024
#define M_   16384
#define NX_  16777216          // B*D*C = M*D
#define DISC_OFF NX_
#define LOSS_OFF (NX_ + M_)

typedef _Float16 h8 __attribute__((ext_vector_type(8)));
typedef float    f4 __attribute__((ext_vector_type(4)));

// Power-of-2 split scales (exact). acc = 2^20 * dot.
#define XSCALE 512.0f
#define ESCALE 2048.0f
#define DOT_UNSCALE_2 (2.0f / 1048576.0f)

// d_ws layout (float offsets).
#define WS_EH  0          // 1M fp16 = 524288 floats
#define WS_EL  524288
#define WS_CN  1048576    // 1024
#define WS_PCN 1049600    // 128*1024 = 131072
#define WS_PV  1180672    // 16384*4 = 65536
#define WS_PI  1246208    // 16384*4 = 65536

__device__ __forceinline__ void async16(const _Float16* g, _Float16* l) {
    __builtin_amdgcn_global_load_lds(
        (const __attribute__((address_space(1))) unsigned int*)g,
        (__attribute__((address_space(3))) unsigned int*)l, 16, 0, 0);
}

// ---------------------------------------------------------------------------
// Fused split kernel. Blocks [0,512): E -> fragment-tiled fp16 hi/lo planes
// [nt][kt][lane][8] + colnorm partials. Blocks [512,8704): x -> same layout.
// ---------------------------------------------------------------------------
__global__ __launch_bounds__(256) void split_kernel(const float* __restrict__ x,
                                                    const float* __restrict__ E,
                                                    _Float16* __restrict__ Xh,
                                                    _Float16* __restrict__ Xl,
                                                    _Float16* __restrict__ Eh,
                                                    _Float16* __restrict__ El,
                                                    float* __restrict__ pcn) {
    const int bid = blockIdx.x;
    if (bid < 512) {
        // ---- E split + colnorm partials ----
        const int tid = bid * 256 + threadIdx.x;      // [0, 131072)
        const int n   = tid & 1023;
        const int o   = tid >> 10;                    // k-octet [0,128)
        const int d0  = o * 8;
        h8 hh, ll;
        float s = 0.f;
        #pragma unroll
        for (int i = 0; i < 8; ++i) {
            const float v = E[(size_t)(d0 + i) * K_ + n];
            s = fmaf(v, v, s);
            const float vs = v * ESCALE;
            const _Float16 h = (_Float16)vs;
            hh[i] = h;
            ll[i] = (_Float16)(vs - (float)h);
        }
        pcn[o * K_ + n] = s;
        const int nt   = n >> 4;
        const int kt   = o >> 2;
        const int lane = (n & 15) + (o & 3) * 16;
        const size_t off = ((size_t)(nt * 32 + kt) * 64 + lane) * 8;
        *(h8*)(Eh + off) = hh;
        *(h8*)(El + off) = ll;
    } else {
        // ---- x split ----
        const int tid = (bid - 512) * 256 + threadIdx.x;  // [0, 2097152)
        const int m   = tid & 16383;
        const int o   = tid >> 14;                        // [0,128)
        const int b   = m >> 8, c = m & 255;
        const int d0  = o * 8;
        const float* xp = x + ((size_t)(b * 1024 + d0) * 256) + c;
        h8 hh, ll;
        #pragma unroll
        for (int i = 0; i < 8; ++i) {
            const float v  = xp[(size_t)i * 256];
            const float vs = v * XSCALE;
            const _Float16 h = (_Float16)vs;
            hh[i] = h;
            ll[i] = (_Float16)(vs - (float)h);
        }
        const int mt   = m >> 4;
        const int kt   = o >> 2;
        const int lane = (m & 15) + (o & 3) * 16;
        const size_t off = ((size_t)(mt * 32 + kt) * 64 + lane) * 8;
        *(h8*)(Xh + off) = hh;
        *(h8*)(Xl + off) = ll;
    }
}

// colnorm: sum the 128 partials per column; zero the loss slot.
__global__ __launch_bounds__(256) void colnorm2_kernel(const float* __restrict__ pcn,
                                                       float* __restrict__ cn,
                                                       float* __restrict__ loss_slot) {
    const int k = blockIdx.x * 256 + threadIdx.x;
    float s = 0.f;
    for (int i = 0; i < 128; ++i) s += pcn[i * K_ + k];
    cn[k] = s;
    if (k == 0) *loss_slot = 0.0f;
}

// ---------------------------------------------------------------------------
// Split-fp16 MFMA distance GEMM + per-block argmin.
// 128x256 tile, 512 threads (8 waves, each 64x64), BK=32, double-buffered LDS
// (2 x 48 KB) with cross-step async prefetch: one barrier per k-step; loads
// for step s+1 issue before compute of step s -> latency hidden by MFMA.
// Grid 512 = 128 rt x 4 ct (consecutive blocks share rt -> A via L3).
// ---------------------------------------------------------------------------
__global__ __launch_bounds__(512, 2) void gemm_argmin_kernel(
        const _Float16* __restrict__ Xh, const _Float16* __restrict__ Xl,
        const _Float16* __restrict__ Eh, const _Float16* __restrict__ El,
        const float* __restrict__ cn,
        float* __restrict__ pV, int* __restrict__ pI) {
    extern __shared__ _Float16 smem[];
    // A buffers: [2][plane*8+mt][512]   (8192 fp16 each)
    // B buffers: [2][plane*16+nt][512]  (16384 fp16 each)
    _Float16* Ab0 = smem;
    _Float16* Ab1 = smem + 8192;
    _Float16* Bb0 = smem + 16384;
    _Float16* Bb1 = smem + 32768;
    float* cV = (float*)(smem + 49152);   // [128][4]
    int*   cI = (int*)(cV + 512);         // [128][4]

    const int t    = threadIdx.x;
    const int rt   = blockIdx.x >> 2;     // 0..127
    const int ct   = blockIdx.x & 3;      // 0..3
    const int wave = t >> 6, lane = t & 63;
    const int lo16 = lane & 15, hi4 = lane >> 4;
    const int mq   = (wave & 1) * 64;
    const int nq   = (wave >> 1) * 64;    // 0,64,128,192
    const int mt0  = rt * 8, nt0 = ct * 16;
    const int n0g  = ct * 256;

    // 48 async chunk-loads per k-step, 6 per wave.
    // id 0..15: A (plane=id>>3, mt=id&7); id 16..47: B (plane=(id-16)>>4, nt=(id-16)&15)
    const _Float16* src[6];
    _Float16* dst0[6];
    _Float16* dst1[6];
    #pragma unroll
    for (int i = 0; i < 6; ++i) {
        const int id = wave * 6 + i;
        if (id < 16) {
            const int plane = id >> 3, mt = id & 7;
            src[i]  = (plane ? Xl : Xh) + ((size_t)(mt0 + mt) * 32) * 512 + lane * 8;
            dst0[i] = Ab0 + (plane * 8 + mt) * 512 + lane * 8;
            dst1[i] = Ab1 + (plane * 8 + mt) * 512 + lane * 8;
        } else {
            const int q = id - 16;
            const int plane = q >> 4, nt = q & 15;
            src[i]  = (plane ? El : Eh) + ((size_t)(nt0 + nt) * 32) * 512 + lane * 8;
            dst0[i] = Bb0 + (plane * 16 + nt) * 512 + lane * 8;
            dst1[i] = Bb1 + (plane * 16 + nt) * 512 + lane * 8;
        }
    }

    f4 acc[4][4];
    const f4 zero = {0.f, 0.f, 0.f, 0.f};
    #pragma unroll
    for (int i = 0; i < 4; ++i)
        #pragma unroll
        for (int j = 0; j < 4; ++j) acc[i][j] = zero;

    // prefetch step 0 into buffer 0
    #pragma unroll
    for (int i = 0; i < 6; ++i) async16(src[i], dst0[i]);

    for (int s = 0; s < 32; ++s) {
        const int cur = s & 1;
        __syncthreads();   // drains own vmcnt: buf[cur] complete; prev compute on buf[cur^1] done
        if (s + 1 < 32) {
            #pragma unroll
            for (int i = 0; i < 6; ++i)
                async16(src[i] + (size_t)(s + 1) * 512, cur ? dst0[i] : dst1[i]);
        }
        const _Float16* Abuf = cur ? Ab1 : Ab0;
        const _Float16* Bbuf = cur ? Bb1 : Bb0;

        h8 Bf[2][4];
        #pragma unroll
        for (int tn = 0; tn < 4; ++tn) {
            const int tixn = (nq >> 4) + tn;
            Bf[0][tn] = *(const h8*)&Bbuf[tixn * 512 + lane * 8];
            Bf[1][tn] = *(const h8*)&Bbuf[(16 + tixn) * 512 + lane * 8];
        }
        #pragma unroll
        for (int tm = 0; tm < 4; ++tm) {
            const int tixm = (mq >> 4) + tm;
            const h8 Ah = *(const h8*)&Abuf[tixm * 512 + lane * 8];
            const h8 Al = *(const h8*)&Abuf[(8 + tixm) * 512 + lane * 8];
            #pragma unroll
            for (int tn = 0; tn < 4; ++tn) {
                acc[tm][tn] = __builtin_amdgcn_mfma_f32_16x16x32_f16(Ah, Bf[0][tn], acc[tm][tn], 0, 0, 0);
                acc[tm][tn] = __builtin_amdgcn_mfma_f32_16x16x32_f16(Ah, Bf[1][tn], acc[tm][tn], 0, 0, 0);
                acc[tm][tn] = __builtin_amdgcn_mfma_f32_16x16x32_f16(Al, Bf[0][tn], acc[tm][tn], 0, 0, 0);
            }
        }
    }

    // ---- epilogue: per-row argmin over this block's 256 cols ----
    float cnv[4];
    #pragma unroll
    for (int tn = 0; tn < 4; ++tn) cnv[tn] = cn[n0g + nq + tn * 16 + lo16];

    #pragma unroll
    for (int tm = 0; tm < 4; ++tm) {
        #pragma unroll
        for (int r = 0; r < 4; ++r) {
            float bv = FLT_MAX;
            int   bi = 0;
            #pragma unroll
            for (int tn = 0; tn < 4; ++tn) {   // ascending col => first-index tie-break
                const float v = cnv[tn] - acc[tm][tn][r] * DOT_UNSCALE_2;
                if (v < bv) { bv = v; bi = nq + tn * 16 + lo16; }
            }
            #pragma unroll
            for (int msk = 1; msk < 16; msk <<= 1) {
                const float ov = __shfl_xor(bv, msk, 64);
                const int   oi = __shfl_xor(bi, msk, 64);
                if (ov < bv || (ov == bv && oi < bi)) { bv = ov; bi = oi; }
            }
            if (lo16 == 0) {
                const int row = mq + tm * 16 + hi4 * 4 + r;
                const int g   = wave >> 1;     // n-quadrant index (ascending n)
                cV[row * 4 + g] = bv;
                cI[row * 4 + g] = bi;
            }
        }
    }
    __syncthreads();
    if (t < 128) {
        float bv = FLT_MAX;
        int   bi = 0;
        #pragma unroll
        for (int g = 0; g < 4; ++g) {          // ascending n-base, strict <
            const float v = cV[t * 4 + g];
            const int   i = cI[t * 4 + g];
            if (v < bv || (v == bv && i < bi)) { bv = v; bi = i; }
        }
        const int row = rt * 128 + t;
        pV[row * 4 + ct] = bv;
        pI[row * 4 + ct] = n0g + bi;
    }
}

// ---------------------------------------------------------------------------
// Final argmin across the 4 col-tiles (ascending, numpy tie-break).
// ---------------------------------------------------------------------------
__global__ __launch_bounds__(256) void reduce_kernel(const float* __restrict__ pV,
                                                     const int* __restrict__ pI,
                                                     float* __restrict__ disc) {
    const int rid = blockIdx.x * 256 + threadIdx.x;
    float bv = FLT_MAX;
    int   bi = 0;
    #pragma unroll
    for (int c = 0; c < 4; ++c) {
        const float v = pV[rid * 4 + c];
        const int   i = pI[rid * 4 + c];
        if (v < bv || (v == bv && i < bi)) { bv = v; bi = i; }
    }
    disc[rid] = (float)bi;
}

// ---------------------------------------------------------------------------
// finalize: one block per d. E row d staged in LDS (4 KB), gather via ds_read.
// q = x + (e - x); loss += 1.25*mean((x-e)^2). Fully coalesced x/q streams.
// ---------------------------------------------------------------------------
__global__ __launch_bounds__(256) void finalize_kernel(const float* __restrict__ x,
                                                       const float* __restrict__ E,
                                                       const float* __restrict__ discf,
                                                       float* __restrict__ out,
                                                       float* __restrict__ loss) {
    __shared__ float Erow[1024];
    const int t = threadIdx.x;
    const int d = blockIdx.x;
    *(float4*)&Erow[t * 4] = *(const float4*)(E + (size_t)d * K_ + t * 4);
    __syncthreads();

    const int bl = t >> 6;           // wave id -> b offset
    const int c4 = (t & 63) * 4;
    float lsum = 0.f;
    #pragma unroll 4
    for (int bg = 0; bg < 64; bg += 4) {
        const int b = bg + bl;
        const float4 id4 = *(const float4*)(discf + b * 256 + c4);
        const size_t xoff = ((size_t)(b * 1024 + d) << 8) + c4;
        const float4 xv = *(const float4*)(x + xoff);
        const float e0 = Erow[(int)id4.x];
        const float e1 = Erow[(int)id4.y];
        const float e2 = Erow[(int)id4.z];
        const float e3 = Erow[(int)id4.w];
        float4 qv;
        qv.x = xv.x + (e0 - xv.x);
        qv.y = xv.y + (e1 - xv.y);
        qv.z = xv.z + (e2 - xv.z);
        qv.w = xv.w + (e3 - xv.w);
        *(float4*)(out + xoff) = qv;
        const float d0 = xv.x - e0, d1 = xv.y - e1, d2 = xv.z - e2, d3 = xv.w - e3;
        lsum += fmaf(d0, d0, fmaf(d1, d1, fmaf(d2, d2, d3 * d3)));
    }

    #pragma unroll
    for (int off = 32; off > 0; off >>= 1)
        lsum += __shfl_down(lsum, off);
    __shared__ float wsum[4];
    if ((t & 63) == 0) wsum[t >> 6] = lsum;
    __syncthreads();
    if (t == 0) {
        const float s = (wsum[0] + wsum[1]) + (wsum[2] + wsum[3]);
        atomicAdd(loss, s * (1.25f / 16777216.0f));
    }
}

// ---------------------------------------------------------------------------
extern "C" void kernel_launch(void* const* d_in, const int* in_sizes, int n_in,
                              void* d_out, int out_size, void* d_ws, size_t ws_size,
                              hipStream_t stream) {
    (void)in_sizes; (void)n_in; (void)out_size; (void)ws_size;
    const float* x = (const float*)d_in[0];   // (64,32,32,256) f32
    const float* E = (const float*)d_in[1];   // (1024,1024)    f32
    float* out = (float*)d_out;
    float* ws  = (float*)d_ws;

    _Float16* Eh = (_Float16*)(ws + WS_EH);
    _Float16* El = (_Float16*)(ws + WS_EL);
    float* cn    = ws + WS_CN;
    float* pcn   = ws + WS_PCN;
    float* pV    = ws + WS_PV;
    int*   pI    = (int*)(ws + WS_PI);

    _Float16* Xh = (_Float16*)out;            // q-region scratch (overwritten by finalize)
    _Float16* Xl = (_Float16*)out + NX_;
    float* disc  = out + DISC_OFF;
    float* loss  = out + LOSS_OFF;

    // Allow 100 KB dynamic LDS (gfx950 WG limit is 160 KB; default cap may be 64 KB).
    static bool attr_set = false;  // idempotent host-side attribute, not a work guard
    hipFuncSetAttribute((const void*)gemm_argmin_kernel,
                        hipFuncAttributeMaxDynamicSharedMemorySize, 102400);
    (void)attr_set;

    split_kernel   <<<8704, 256, 0, stream>>>(x, E, Xh, Xl, Eh, El, pcn);
    colnorm2_kernel<<<4,    256, 0, stream>>>(pcn, cn, loss);
    gemm_argmin_kernel<<<512, 512, 102400, stream>>>(Xh, Xl, Eh, El, cn, pV, pI);
    reduce_kernel  <<<64,   256, 0, stream>>>(pV, pI, disc);
    finalize_kernel<<<1024, 256, 0, stream>>>(x, E, disc, out, loss);
}